// Round 6
// baseline (613.324 us; speedup 1.0000x reference)
//
#include <hip/hip_runtime.h>
#include <stdint.h>

#define BB 4
#define SS 2048
#define HIDW 2048
#define NH 16
#define NKV 4
#define DD 128

typedef unsigned short u16;
typedef unsigned long long u64;
typedef unsigned int uint;
typedef __attribute__((ext_vector_type(8))) short bf16x8;
typedef __attribute__((ext_vector_type(4))) float f32x4;
typedef __attribute__((ext_vector_type(2))) float f32x2;
typedef __attribute__((ext_vector_type(2))) __bf16 bf16x2;

__device__ __forceinline__ u16 f2bf1(float f) {
  __bf16 h = (__bf16)f;
  return __builtin_bit_cast(u16, h);
}

__device__ __forceinline__ float bf2f(u16 v) {
  return __uint_as_float((uint)v << 16);
}

// packed f32 pair -> bf16 pair (v_cvt_pk_bf16_f32 on gfx950)
__device__ __forceinline__ uint pkbf(float a, float b) {
  f32x2 v = {a, b};
  bf16x2 h = __builtin_convertvector(v, bf16x2);
  return __builtin_bit_cast(uint, h);
}

__device__ __forceinline__ void gld_lds16(const void* g, void* s) {
  __builtin_amdgcn_global_load_lds(
      (const __attribute__((address_space(1))) void*)g,
      (__attribute__((address_space(3))) void*)(unsigned)(uintptr_t)s,
      16, 0, 0);
}

// ---------------- fp32 -> bf16 cast ----------------
__global__ __launch_bounds__(256) void cast_f32_bf16(const float* __restrict__ in,
                                                     u16* __restrict__ out, int n4) {
  int i = blockIdx.x * 256 + threadIdx.x;
  if (i < n4) {
    float4 f = ((const float4*)in)[i];
    uint2 o;
    o.x = pkbf(f.x, f.y);
    o.y = pkbf(f.z, f.w);
    ((uint2*)out)[i] = o;
  }
}

// ---------------- m97-style GEMM: C(f32, MxN) = A(bf16 MxK) * Bt(bf16 NxK)^T ----
__global__ __launch_bounds__(256) void gemm_bt(const u16* __restrict__ A,
                                               const u16* __restrict__ Bt,
                                               float* __restrict__ C,
                                               int M, int N, int K) {
  __shared__ u16 As[128 * 32];
  __shared__ u16 Bs[128 * 32];
  const int tid = threadIdx.x;
  const int wave = tid >> 6, lane = tid & 63;
  const int lr = lane & 15, lq = lane >> 4;
  const int row0 = blockIdx.y * 128, col0 = blockIdx.x * 128;
  const int wm = (wave >> 1) * 64, wn = (wave & 1) * 64;

  const int trow = tid >> 2;
  const int tblk = (tid & 3) ^ (trow & 3);
  const u16* aSrc = A + (size_t)(row0 + trow) * K + tblk * 8;
  const u16* bSrc = Bt + (size_t)(col0 + trow) * K + tblk * 8;
  char* ldsA = (char*)As + wave * 1024;
  char* ldsB = (char*)Bs + wave * 1024;

  f32x4 acc[4][4] = {};
  const int aoff = (wm + lr) * 32 + ((lq ^ (lr & 3)) * 8);
  const int boff = (wn + lr) * 32 + ((lq ^ (lr & 3)) * 8);

  for (int k0 = 0; k0 < K; k0 += 32) {
    __syncthreads();
    gld_lds16(aSrc + k0, ldsA);
    gld_lds16(aSrc + (size_t)64 * K + k0, ldsA + 4096);
    gld_lds16(bSrc + k0, ldsB);
    gld_lds16(bSrc + (size_t)64 * K + k0, ldsB + 4096);
    __syncthreads();
    bf16x8 a[4], b[4];
#pragma unroll
    for (int i = 0; i < 4; i++) a[i] = *(const bf16x8*)(As + aoff + i * 512);
#pragma unroll
    for (int j = 0; j < 4; j++) b[j] = *(const bf16x8*)(Bs + boff + j * 512);
#pragma unroll
    for (int i = 0; i < 4; i++)
#pragma unroll
      for (int j = 0; j < 4; j++)
        acc[i][j] = __builtin_amdgcn_mfma_f32_16x16x32_bf16(a[i], b[j], acc[i][j], 0, 0, 0);
  }
#pragma unroll
  for (int i = 0; i < 4; i++) {
    int row = row0 + wm + i * 16 + lq * 4;
#pragma unroll
    for (int j = 0; j < 4; j++) {
      int col = col0 + wn + j * 16 + lr;
      float* cp = C + (size_t)row * N + col;
#pragma unroll
      for (int r = 0; r < 4; r++) cp[(size_t)r * N] = acc[i][j][r];
    }
  }
}

// ---------------- same GEMM but bf16 output ----------------
__global__ __launch_bounds__(256) void gemm_bt_bf16(const u16* __restrict__ A,
                                                    const u16* __restrict__ Bt,
                                                    u16* __restrict__ C,
                                                    int M, int N, int K) {
  __shared__ u16 As[128 * 32];
  __shared__ u16 Bs[128 * 32];
  const int tid = threadIdx.x;
  const int wave = tid >> 6, lane = tid & 63;
  const int lr = lane & 15, lq = lane >> 4;
  const int row0 = blockIdx.y * 128, col0 = blockIdx.x * 128;
  const int wm = (wave >> 1) * 64, wn = (wave & 1) * 64;

  const int trow = tid >> 2;
  const int tblk = (tid & 3) ^ (trow & 3);
  const u16* aSrc = A + (size_t)(row0 + trow) * K + tblk * 8;
  const u16* bSrc = Bt + (size_t)(col0 + trow) * K + tblk * 8;
  char* ldsA = (char*)As + wave * 1024;
  char* ldsB = (char*)Bs + wave * 1024;

  f32x4 acc[4][4] = {};
  const int aoff = (wm + lr) * 32 + ((lq ^ (lr & 3)) * 8);
  const int boff = (wn + lr) * 32 + ((lq ^ (lr & 3)) * 8);

  for (int k0 = 0; k0 < K; k0 += 32) {
    __syncthreads();
    gld_lds16(aSrc + k0, ldsA);
    gld_lds16(aSrc + (size_t)64 * K + k0, ldsA + 4096);
    gld_lds16(bSrc + k0, ldsB);
    gld_lds16(bSrc + (size_t)64 * K + k0, ldsB + 4096);
    __syncthreads();
    bf16x8 a[4], b[4];
#pragma unroll
    for (int i = 0; i < 4; i++) a[i] = *(const bf16x8*)(As + aoff + i * 512);
#pragma unroll
    for (int j = 0; j < 4; j++) b[j] = *(const bf16x8*)(Bs + boff + j * 512);
#pragma unroll
    for (int i = 0; i < 4; i++)
#pragma unroll
      for (int j = 0; j < 4; j++)
        acc[i][j] = __builtin_amdgcn_mfma_f32_16x16x32_bf16(a[i], b[j], acc[i][j], 0, 0, 0);
  }
#pragma unroll
  for (int i = 0; i < 4; i++) {
    int row = row0 + wm + i * 16 + lq * 4;
#pragma unroll
    for (int j = 0; j < 4; j++) {
      int col = col0 + wn + j * 16 + lr;
      u16* cp = C + (size_t)row * N + col;
#pragma unroll
      for (int r = 0; r < 4; r++) cp[(size_t)r * N] = f2bf1(acc[i][j][r]);
    }
  }
}

// ---------------- RoPE on fused qkv bf16 [tok][3072] -> bf16 head layouts ------
__global__ __launch_bounds__(256) void rope_qk(const u16* __restrict__ qkv,
                                               const float* __restrict__ cosT,
                                               const float* __restrict__ sinT,
                                               u16* __restrict__ qb, u16* __restrict__ kb) {
  const float qscale = 0.08838834764831845f;  // 1/sqrt(128)
  int tok = blockIdx.x;
  int b = tok >> 11, s = tok & (SS - 1);
  for (int p = threadIdx.x; p < (NH + NKV) * 64; p += 256) {
    int head = p >> 6, dd = p & 63;
    float c0 = cosT[s * DD + dd];
    float c1 = cosT[s * DD + dd + 64];
    float s0 = sinT[s * DD + dd];
    float s1 = sinT[s * DD + dd + 64];
    if (head < NH) {
      const u16* src = qkv + (size_t)tok * 3072 + head * DD;
      float x0 = bf2f(src[dd]), x1 = bf2f(src[dd + 64]);
      u16* dst = qb + ((size_t)(b * NH + head) * SS + s) * DD;
      dst[dd] = f2bf1((x0 * c0 - x1 * s0) * qscale);
      dst[dd + 64] = f2bf1((x1 * c1 + x0 * s1) * qscale);
    } else {
      int kv = head - NH;
      const u16* src = qkv + (size_t)tok * 3072 + 2048 + kv * DD;
      float x0 = bf2f(src[dd]), x1 = bf2f(src[dd + 64]);
      u16* dst = kb + ((size_t)(b * NKV + kv) * SS + s) * DD;
      dst[dd] = f2bf1(x0 * c0 - x1 * s0);
      dst[dd + 64] = f2bf1(x1 * c1 + x0 * s1);
    }
  }
}

// ---------------- V transpose: qkv bf16 [tok][2560+kv*128+d] -> vt[b][kv][d][s] -
__global__ __launch_bounds__(256) void v_trans(const u16* __restrict__ qkv,
                                               u16* __restrict__ vt) {
  __shared__ u16 tile[64][66];
  int bk = blockIdx.x;  // b*NKV+kv
  int b = bk >> 2, kv = bk & 3;
  int s0 = blockIdx.y * 64, d0 = blockIdx.z * 64;
  int t = threadIdx.x;
  int sl = t >> 2, dc = (t & 3) * 16;
  const u16* src = qkv + ((size_t)(b * SS + s0 + sl)) * 3072 + 2560 + kv * DD + d0 + dc;
  uint4 a0 = *(const uint4*)src;
  uint4 a1 = *(const uint4*)(src + 8);
  uint* lrow = (uint*)&tile[sl][dc];
  lrow[0] = a0.x; lrow[1] = a0.y; lrow[2] = a0.z; lrow[3] = a0.w;
  lrow[4] = a1.x; lrow[5] = a1.y; lrow[6] = a1.z; lrow[7] = a1.w;
  __syncthreads();
  int dl = t >> 2, sc = (t & 3) * 16;
  u16* dst = vt + ((size_t)bk * DD + d0 + dl) * SS + s0 + sc;
  uint4 o0, o1;
  o0.x = (uint)tile[sc + 0][dl] | ((uint)tile[sc + 1][dl] << 16);
  o0.y = (uint)tile[sc + 2][dl] | ((uint)tile[sc + 3][dl] << 16);
  o0.z = (uint)tile[sc + 4][dl] | ((uint)tile[sc + 5][dl] << 16);
  o0.w = (uint)tile[sc + 6][dl] | ((uint)tile[sc + 7][dl] << 16);
  o1.x = (uint)tile[sc + 8][dl] | ((uint)tile[sc + 9][dl] << 16);
  o1.y = (uint)tile[sc + 10][dl] | ((uint)tile[sc + 11][dl] << 16);
  o1.z = (uint)tile[sc + 12][dl] | ((uint)tile[sc + 13][dl] << 16);
  o1.w = (uint)tile[sc + 14][dl] | ((uint)tile[sc + 15][dl] << 16);
  *(uint4*)dst = o0;
  *(uint4*)(dst + 8) = o1;
}

// ---------------- transposed flash attention v3 --------------------------------
// LDS-traffic-per-FLOP cut: 64 q-rows per wave (nt=4), 256 q per block. Every
// K/V A-fragment read from LDS now feeds 4 MFMAs (was 2). Exact softmax (no
// running max; scores bounded). Single-buffered Ks/Vs (dbuf was neutral),
// Pt 256x64. LDS = 16+16+32 = 64 KB.
__global__ __launch_bounds__(256) void flash_attn(const u16* __restrict__ qb,
                                                  const u16* __restrict__ kb,
                                                  const u16* __restrict__ vt,
                                                  u16* __restrict__ ob) {
  __shared__ u16 Ks[64 * 128];    // [kv][d], 16B-blk swizzle ^ (row&15)
  __shared__ u16 Vs[128 * 64];    // [d][s],  16B-blk swizzle ^ (row&7)
  __shared__ u16 Pt[256 * 64];    // [q][kv], 16B-blk swizzle ^ (row&7)
  const int tid = threadIdx.x;
  const int wave = tid >> 6, lane = tid & 63;
  const int lr = lane & 15, lq = lane >> 4;

  // XCD swizzle: 512 blocks, xcd = lin&7; 2 (b,kvh) pairs per XCD so each
  // XCD L2 holds ~2 MB of K/V.
  const int lin = blockIdx.y * 8 + blockIdx.x;
  const int xcd = lin & 7;
  const int slot = lin >> 3;               // 0..63
  const int pr = xcd + ((slot & 1) << 3);  // (b,kvh) 0..15
  const int b = pr >> 2, kvh = pr & 3;
  const int rest = slot >> 1;              // 0..31
  const int h = kvh * 4 + (rest & 3);
  const int q0 = (rest >> 2) * 256;
  const int bh = b * 16 + h;

  const size_t kbase = (size_t)(b * NKV + kvh) * SS * DD;
  const size_t vbase = (size_t)(b * NKV + kvh) * DD * SS;

  // Q fragments from global (B-operand: n=qrow via lr, 8 contig d per octet)
  bf16x8 qf[4][4];
#pragma unroll
  for (int nt = 0; nt < 4; nt++) {
    const u16* qrow = qb + ((size_t)bh * SS + q0 + wave * 64 + nt * 16 + lr) * DD + lq * 8;
#pragma unroll
    for (int kk = 0; kk < 4; kk++) qf[nt][kk] = *(const bf16x8*)(qrow + kk * 32);
  }

  f32x4 o_acc[8][4] = {};
  float l_i[4] = {0.0f, 0.0f, 0.0f, 0.0f};

  const int ktrow = tid >> 4;                  // 0..15
  const int ktblk = (tid & 15) ^ ktrow;
  const u16* ksrc = kb + kbase + (size_t)ktrow * DD + ktblk * 8;
  const int vtrow = tid >> 3;                  // 0..31
  const int vtblk = (tid & 7) ^ (vtrow & 7);
  const u16* vsrc = vt + vbase + (size_t)vtrow * SS + vtblk * 8;
  char* kdst = (char*)Ks + wave * 1024;
  char* vdst = (char*)Vs + wave * 1024;

  for (int s0 = 0; s0 < SS; s0 += 64) {
    __syncthreads();
#pragma unroll
    for (int c = 0; c < 4; c++) {
      gld_lds16(ksrc + (size_t)(s0 + c * 16) * DD, kdst + c * 4096);
      gld_lds16(vsrc + s0 + (size_t)c * 32 * SS, vdst + c * 4096);
    }
    __syncthreads();

    // S^T tiles: sc[mt][nt] = S^T[kv=mt*16+lq*4+r][q=wave*64+nt*16+lr]
    f32x4 sc[4][4] = {};
#pragma unroll
    for (int kk = 0; kk < 4; kk++) {
#pragma unroll
      for (int mt = 0; mt < 4; mt++) {
        bf16x8 kf = *(const bf16x8*)(Ks + (mt * 16 + lr) * 128 + (((kk * 4 + lq) ^ lr) * 8));
#pragma unroll
        for (int nt = 0; nt < 4; nt++)
          sc[mt][nt] = __builtin_amdgcn_mfma_f32_16x16x32_bf16(kf, qf[nt][kk], sc[mt][nt], 0, 0, 0);
      }
    }

#pragma unroll
    for (int nt = 0; nt < 4; nt++) {
      float rs = 0.0f;
#pragma unroll
      for (int mt = 0; mt < 4; mt++)
#pragma unroll
        for (int r = 0; r < 4; r++) {
          float p = __expf(sc[mt][nt][r]);
          sc[mt][nt][r] = p;
          rs += p;
        }
      l_i[nt] += rs;
      // P^T -> Pt[q][kv] single b64 store (wave-private rows, no barrier)
      int prow = wave * 64 + nt * 16 + lr;
#pragma unroll
      for (int mt = 0; mt < 4; mt++) {
        u64 pw = (u64)pkbf(sc[mt][nt][0], sc[mt][nt][1]) |
                 ((u64)pkbf(sc[mt][nt][2], sc[mt][nt][3]) << 32);
        int bb = (mt * 2 + (lq >> 1)) ^ (lr & 7);
        *(u64*)((char*)Pt + prow * 128 + bb * 16 + (lq & 1) * 8) = pw;
      }
    }

    // O^T += V^T * P^T : o_acc[mt][nt] = O^T[d=mt*16+lq*4+r][q=wave*64+nt*16+lr]
#pragma unroll
    for (int kk2 = 0; kk2 < 2; kk2++) {
      bf16x8 pbf[4];
#pragma unroll
      for (int nt = 0; nt < 4; nt++) {
        int prow = wave * 64 + nt * 16 + lr;
        pbf[nt] = *(const bf16x8*)((char*)Pt + prow * 128 + (((kk2 * 4 + lq) ^ (lr & 7)) * 16));
      }
#pragma unroll
      for (int mt = 0; mt < 8; mt++) {
        bf16x8 vf = *(const bf16x8*)(Vs + (mt * 16 + lr) * 64 + (((kk2 * 4 + lq) ^ (lr & 7)) * 8));
#pragma unroll
        for (int nt = 0; nt < 4; nt++)
          o_acc[mt][nt] = __builtin_amdgcn_mfma_f32_16x16x32_bf16(vf, pbf[nt], o_acc[mt][nt], 0, 0, 0);
      }
    }
  }

#pragma unroll
  for (int nt = 0; nt < 4; nt++) {
    float l = l_i[nt];
    l += __shfl_xor(l, 16, 64);
    l += __shfl_xor(l, 32, 64);
    float inv = 1.0f / l;
    size_t q = (size_t)q0 + wave * 64 + nt * 16 + lr;
    u16* dst = ob + ((size_t)b * SS + q) * HIDW + h * DD + lq * 4;
#pragma unroll
    for (int mt = 0; mt < 8; mt++) {
      uint2 pk;
      pk.x = pkbf(o_acc[mt][nt][0] * inv, o_acc[mt][nt][1] * inv);
      pk.y = pkbf(o_acc[mt][nt][2] * inv, o_acc[mt][nt][3] * inv);
      *(uint2*)(dst + mt * 16) = pk;
    }
  }
}

extern "C" void kernel_launch(void* const* d_in, const int* in_sizes, int n_in,
                              void* d_out, int out_size, void* d_ws, size_t ws_size,
                              hipStream_t stream) {
  const float* x = (const float*)d_in[0];
  const float* cosT = (const float*)d_in[1];
  const float* sinT = (const float*)d_in[2];
  const float* wq = (const float*)d_in[3];
  const float* wk = (const float*)d_in[4];
  const float* wv = (const float*)d_in[5];
  const float* wo = (const float*)d_in[6];
  float* out = (float*)d_out;

  char* ws = (char*)d_ws;
  size_t off = 0;
  auto alloc = [&](size_t bytes) {
    char* p = ws + off;
    off += (bytes + 255) & ~(size_t)255;
    return p;
  };
  const int M = BB * SS;
  u16* xb = (u16*)alloc((size_t)M * HIDW * 2);
  u16* wqkvb = (u16*)alloc((size_t)3072 * HIDW * 2);  // wq|wk|wv contiguous
  u16* wob = (u16*)alloc((size_t)HIDW * NH * DD * 2);
  u16* qkvb = (u16*)alloc((size_t)M * 3072 * 2);
  u16* qb = (u16*)alloc((size_t)BB * NH * SS * DD * 2);
  u16* kb = (u16*)alloc((size_t)BB * NKV * SS * DD * 2);
  u16* vt = (u16*)alloc((size_t)BB * NKV * DD * SS * 2);
  u16* ob = qkvb;  // alias: qkvb dead after rope_qk/v_trans

  cast_f32_bf16<<<(M * HIDW) / 1024, 256, 0, stream>>>(x, xb, (M * HIDW) / 4);
  cast_f32_bf16<<<(2048 * HIDW) / 1024, 256, 0, stream>>>(wq, wqkvb, (2048 * HIDW) / 4);
  cast_f32_bf16<<<(512 * HIDW) / 1024, 256, 0, stream>>>(wk, wqkvb + (size_t)2048 * HIDW,
                                                         (512 * HIDW) / 4);
  cast_f32_bf16<<<(512 * HIDW) / 1024, 256, 0, stream>>>(wv, wqkvb + (size_t)2560 * HIDW,
                                                         (512 * HIDW) / 4);
  cast_f32_bf16<<<(HIDW * NH * DD) / 1024, 256, 0, stream>>>(wo, wob, (HIDW * NH * DD) / 4);

  gemm_bt_bf16<<<dim3(3072 / 128, M / 128), 256, 0, stream>>>(xb, wqkvb, qkvb, M, 3072, HIDW);

  rope_qk<<<M, 256, 0, stream>>>(qkvb, cosT, sinT, qb, kb);
  v_trans<<<dim3(BB * NKV, SS / 64, DD / 64), 256, 0, stream>>>(qkvb, vt);

  flash_attn<<<dim3(SS / 256, BB * NH), 256, 0, stream>>>(qb, kb, vt, ob);

  gemm_bt<<<dim3(HIDW / 128, M / 128), 256, 0, stream>>>(ob, wob, out, M, HIDW, NH * DD);
}

// Round 7
// 535.230 us; speedup vs baseline: 1.1459x; 1.1459x over previous
//
#include <hip/hip_runtime.h>
#include <stdint.h>

#define BB 4
#define SS 2048
#define HIDW 2048
#define NH 16
#define NKV 4
#define DD 128

typedef unsigned short u16;
typedef unsigned long long u64;
typedef unsigned int uint;
typedef __attribute__((ext_vector_type(8))) short bf16x8;
typedef __attribute__((ext_vector_type(4))) float f32x4;
typedef __attribute__((ext_vector_type(2))) float f32x2;
typedef __attribute__((ext_vector_type(2))) __bf16 bf16x2;

__device__ __forceinline__ u16 f2bf1(float f) {
  __bf16 h = (__bf16)f;
  return __builtin_bit_cast(u16, h);
}

__device__ __forceinline__ float bf2f(u16 v) {
  return __uint_as_float((uint)v << 16);
}

// packed f32 pair -> bf16 pair (v_cvt_pk_bf16_f32 on gfx950)
__device__ __forceinline__ uint pkbf(float a, float b) {
  f32x2 v = {a, b};
  bf16x2 h = __builtin_convertvector(v, bf16x2);
  return __builtin_bit_cast(uint, h);
}

__device__ __forceinline__ void gld_lds16(const void* g, void* s) {
  __builtin_amdgcn_global_load_lds(
      (const __attribute__((address_space(1))) void*)g,
      (__attribute__((address_space(3))) void*)(unsigned)(uintptr_t)s,
      16, 0, 0);
}

// ---------------- fp32 -> bf16 cast (x) ----------------
__global__ __launch_bounds__(256) void cast_f32_bf16(const float* __restrict__ in,
                                                     u16* __restrict__ out, int n4) {
  int i = blockIdx.x * 256 + threadIdx.x;
  if (i < n4) {
    float4 f = ((const float4*)in)[i];
    uint2 o;
    o.x = pkbf(f.x, f.y);
    o.y = pkbf(f.z, f.w);
    ((uint2*)out)[i] = o;
  }
}

// ---------------- all 4 weight casts in one launch ----------------
// wq (4.19M el) -> wqkvb[0..], wk -> wqkvb+2048*2048, wv -> wqkvb+2560*2048,
// wo -> wob. Indexed in uint2 (4-elem) units.
__global__ __launch_bounds__(256) void cast_weights(const float* __restrict__ wq,
                                                    const float* __restrict__ wk,
                                                    const float* __restrict__ wv,
                                                    const float* __restrict__ wo,
                                                    u16* __restrict__ wqkvb,
                                                    u16* __restrict__ wob) {
  int i = blockIdx.x * 256 + threadIdx.x;
  const float* src;
  uint2* dst;
  int off;
  if (i < 1048576) {
    src = wq; dst = (uint2*)wqkvb; off = i;
  } else if (i < 1310720) {
    src = wk; dst = (uint2*)(wqkvb + (size_t)2048 * 2048); off = i - 1048576;
  } else if (i < 1572864) {
    src = wv; dst = (uint2*)(wqkvb + (size_t)2560 * 2048); off = i - 1310720;
  } else {
    src = wo; dst = (uint2*)wob; off = i - 1572864;
  }
  float4 f = ((const float4*)src)[off];
  uint2 o;
  o.x = pkbf(f.x, f.y);
  o.y = pkbf(f.z, f.w);
  dst[off] = o;
}

// ---------------- m97-style GEMM: C(f32, MxN) = A(bf16 MxK) * Bt(bf16 NxK)^T ----
__global__ __launch_bounds__(256) void gemm_bt(const u16* __restrict__ A,
                                               const u16* __restrict__ Bt,
                                               float* __restrict__ C,
                                               int M, int N, int K) {
  __shared__ u16 As[128 * 32];
  __shared__ u16 Bs[128 * 32];
  const int tid = threadIdx.x;
  const int wave = tid >> 6, lane = tid & 63;
  const int lr = lane & 15, lq = lane >> 4;
  const int row0 = blockIdx.y * 128, col0 = blockIdx.x * 128;
  const int wm = (wave >> 1) * 64, wn = (wave & 1) * 64;

  const int trow = tid >> 2;
  const int tblk = (tid & 3) ^ (trow & 3);
  const u16* aSrc = A + (size_t)(row0 + trow) * K + tblk * 8;
  const u16* bSrc = Bt + (size_t)(col0 + trow) * K + tblk * 8;
  char* ldsA = (char*)As + wave * 1024;
  char* ldsB = (char*)Bs + wave * 1024;

  f32x4 acc[4][4] = {};
  const int aoff = (wm + lr) * 32 + ((lq ^ (lr & 3)) * 8);
  const int boff = (wn + lr) * 32 + ((lq ^ (lr & 3)) * 8);

  for (int k0 = 0; k0 < K; k0 += 32) {
    __syncthreads();
    gld_lds16(aSrc + k0, ldsA);
    gld_lds16(aSrc + (size_t)64 * K + k0, ldsA + 4096);
    gld_lds16(bSrc + k0, ldsB);
    gld_lds16(bSrc + (size_t)64 * K + k0, ldsB + 4096);
    __syncthreads();
    bf16x8 a[4], b[4];
#pragma unroll
    for (int i = 0; i < 4; i++) a[i] = *(const bf16x8*)(As + aoff + i * 512);
#pragma unroll
    for (int j = 0; j < 4; j++) b[j] = *(const bf16x8*)(Bs + boff + j * 512);
#pragma unroll
    for (int i = 0; i < 4; i++)
#pragma unroll
      for (int j = 0; j < 4; j++)
        acc[i][j] = __builtin_amdgcn_mfma_f32_16x16x32_bf16(a[i], b[j], acc[i][j], 0, 0, 0);
  }
#pragma unroll
  for (int i = 0; i < 4; i++) {
    int row = row0 + wm + i * 16 + lq * 4;
#pragma unroll
    for (int j = 0; j < 4; j++) {
      int col = col0 + wn + j * 16 + lr;
      float* cp = C + (size_t)row * N + col;
#pragma unroll
      for (int r = 0; r < 4; r++) cp[(size_t)r * N] = acc[i][j][r];
    }
  }
}

// ---------------- fused QKV GEMM + RoPE + head scatter + V transpose -----------
// Wave tile m=32 x n=128: each lane holds cols d=j*16+lr for j=0..7, so the
// rotary pair (d, d+64) = (j, j+4) is in-register. cos[s][d]==cos[s][d+64]
// (emb = concat(freqs,freqs)). Writes qb[b][h][s][d] (scaled 1/sqrt(D)),
// kb[b][kv][s][d], vt[b][kv][d][s] directly -- no qkv intermediate.
__global__ __launch_bounds__(256) void gemm_qkv_rope(const u16* __restrict__ A,
                                                     const u16* __restrict__ Bt,
                                                     const float* __restrict__ cosT,
                                                     const float* __restrict__ sinT,
                                                     u16* __restrict__ qb,
                                                     u16* __restrict__ kb,
                                                     u16* __restrict__ vt) {
  __shared__ u16 As[128 * 32];
  __shared__ u16 Bs[128 * 32];
  const int tid = threadIdx.x;
  const int wave = tid >> 6, lane = tid & 63;
  const int lr = lane & 15, lq = lane >> 4;
  const int row0 = blockIdx.y * 128, col0 = blockIdx.x * 128;
  const int K = HIDW;

  const int trow = tid >> 2;
  const int tblk = (tid & 3) ^ (trow & 3);
  const u16* aSrc = A + (size_t)(row0 + trow) * K + tblk * 8;
  const u16* bSrc = Bt + (size_t)(col0 + trow) * K + tblk * 8;
  char* ldsA = (char*)As + wave * 1024;
  char* ldsB = (char*)Bs + wave * 1024;

  f32x4 acc[2][8] = {};
  const int aoff = (wave * 32 + lr) * 32 + ((lq ^ (lr & 3)) * 8);
  const int boff = lr * 32 + ((lq ^ (lr & 3)) * 8);

  for (int k0 = 0; k0 < K; k0 += 32) {
    __syncthreads();
    gld_lds16(aSrc + k0, ldsA);
    gld_lds16(aSrc + (size_t)64 * K + k0, ldsA + 4096);
    gld_lds16(bSrc + k0, ldsB);
    gld_lds16(bSrc + (size_t)64 * K + k0, ldsB + 4096);
    __syncthreads();
    bf16x8 a[2], b[8];
#pragma unroll
    for (int i = 0; i < 2; i++) a[i] = *(const bf16x8*)(As + aoff + i * 512);
#pragma unroll
    for (int j = 0; j < 8; j++) b[j] = *(const bf16x8*)(Bs + boff + j * 512);
#pragma unroll
    for (int i = 0; i < 2; i++)
#pragma unroll
      for (int j = 0; j < 8; j++)
        acc[i][j] = __builtin_amdgcn_mfma_f32_16x16x32_bf16(a[i], b[j], acc[i][j], 0, 0, 0);
  }

  const int b_ = row0 >> 11;          // batch (tile never crosses: 2048%128==0)
  const int s_base = (row0 & (SS - 1)) + wave * 32;
  const int hsel = col0 >> 7;         // 0..15 q-head, 16..19 k-head, 20..23 v-head

  if (hsel < 20) {
    const float scale = (hsel < 16) ? 0.08838834764831845f : 1.0f;
    u16* base = (hsel < 16)
                    ? qb + (size_t)(b_ * NH + hsel) * SS * DD
                    : kb + (size_t)(b_ * NKV + (hsel - 16)) * SS * DD;
#pragma unroll
    for (int i = 0; i < 2; i++) {
#pragma unroll
      for (int r = 0; r < 4; r++) {
        int s = s_base + i * 16 + lq * 4 + r;
        const float* cp = cosT + (size_t)s * DD;
        const float* sp = sinT + (size_t)s * DD;
        u16* drow = base + (size_t)s * DD;
#pragma unroll
        for (int j = 0; j < 4; j++) {
          int d = j * 16 + lr;
          float c = cp[d], si = sp[d];
          float x0 = acc[i][j][r] * scale, x1 = acc[i][j + 4][r] * scale;
          drow[d] = f2bf1(x0 * c - x1 * si);
          drow[d + 64] = f2bf1(x1 * c + x0 * si);
        }
      }
    }
  } else {
    const int kv = hsel - 20;
#pragma unroll
    for (int i = 0; i < 2; i++) {
      int s = s_base + i * 16 + lq * 4;
#pragma unroll
      for (int j = 0; j < 8; j++) {
        int d = j * 16 + lr;
        u64 pw = (u64)pkbf(acc[i][j][0], acc[i][j][1]) |
                 ((u64)pkbf(acc[i][j][2], acc[i][j][3]) << 32);
        *(u64*)(vt + (size_t)((b_ * NKV + kv) * DD + d) * SS + s) = pw;
      }
    }
  }
}

// ---------------- transposed flash attention (r5 version -- best measured) -----
// Exact softmax (scores bounded, no running max). 128 q-rows/block, 4 waves x
// 32 q-rows. XCD-aware swizzle (2 (b,kvh) pairs per XCD L2); 2 KV tiles per
// barrier, double-buffered K/V LDS; Pt single b64 store.
__global__ __launch_bounds__(256, 2) void flash_attn(const u16* __restrict__ qb,
                                                     const u16* __restrict__ kb,
                                                     const u16* __restrict__ vt,
                                                     u16* __restrict__ ob) {
  __shared__ u16 Ks[2][64 * 128];  // [kv][d], 16B-blk swizzle ^ (row&15)
  __shared__ u16 Vs[2][128 * 64];  // [d][s],  16B-blk swizzle ^ (row&7)
  __shared__ u16 Pt[128 * 64];     // [q][kv], 16B-blk swizzle ^ (row&7)
  const int tid = threadIdx.x;
  const int wave = tid >> 6, lane = tid & 63;
  const int lr = lane & 15, lq = lane >> 4;

  const int lin = blockIdx.y * 16 + blockIdx.x;
  const int xcd = lin & 7;
  const int slot = lin >> 3;               // 0..127
  const int pr = xcd + ((slot & 1) << 3);  // (b,kvh) id 0..15
  const int b = pr >> 2, kvh = pr & 3;
  const int rest = slot >> 1;              // 0..63
  const int h = kvh * 4 + (rest & 3);
  const int q0 = (rest >> 2) * 128;
  const int bh = b * 16 + h;

  const size_t kbase = (size_t)(b * NKV + kvh) * SS * DD;
  const size_t vbase = (size_t)(b * NKV + kvh) * DD * SS;

  bf16x8 qf[2][4];
#pragma unroll
  for (int nt = 0; nt < 2; nt++) {
    const u16* qrow = qb + ((size_t)bh * SS + q0 + wave * 32 + nt * 16 + lr) * DD + lq * 8;
#pragma unroll
    for (int kk = 0; kk < 4; kk++) qf[nt][kk] = *(const bf16x8*)(qrow + kk * 32);
  }

  f32x4 o_acc[8][2] = {};
  float l_i[2] = {0.0f, 0.0f};

  const int ktrow = tid >> 4;
  const int ktblk = (tid & 15) ^ ktrow;
  const u16* ksrc = kb + kbase + (size_t)ktrow * DD + ktblk * 8;
  const int vtrow = tid >> 3;
  const int vtblk = (tid & 7) ^ (vtrow & 7);
  const u16* vsrc = vt + vbase + (size_t)vtrow * SS + vtblk * 8;

  for (int s0 = 0; s0 < SS; s0 += 128) {
    __syncthreads();
#pragma unroll
    for (int hb = 0; hb < 2; hb++) {
      const u16* kS = ksrc + (size_t)(s0 + hb * 64) * DD;
      const u16* vS = vsrc + s0 + hb * 64;
      char* kd = (char*)(Ks[hb]) + wave * 1024;
      char* vd = (char*)(Vs[hb]) + wave * 1024;
#pragma unroll
      for (int c = 0; c < 4; c++) {
        gld_lds16(kS + (size_t)c * 16 * DD, kd + c * 4096);
        gld_lds16(vS + (size_t)c * 32 * SS, vd + c * 4096);
      }
    }
    __syncthreads();

#pragma unroll
    for (int hb = 0; hb < 2; hb++) {
      const u16* K = Ks[hb];
      const u16* V = Vs[hb];

      f32x4 sc[4][2] = {};
#pragma unroll
      for (int kk = 0; kk < 4; kk++) {
#pragma unroll
        for (int mt = 0; mt < 4; mt++) {
          bf16x8 kf = *(const bf16x8*)(K + (mt * 16 + lr) * 128 + (((kk * 4 + lq) ^ lr) * 8));
#pragma unroll
          for (int nt = 0; nt < 2; nt++)
            sc[mt][nt] = __builtin_amdgcn_mfma_f32_16x16x32_bf16(kf, qf[nt][kk], sc[mt][nt], 0, 0, 0);
        }
      }

#pragma unroll
      for (int nt = 0; nt < 2; nt++) {
        float rs = 0.0f;
#pragma unroll
        for (int mt = 0; mt < 4; mt++)
#pragma unroll
          for (int r = 0; r < 4; r++) {
            float p = __expf(sc[mt][nt][r]);
            sc[mt][nt][r] = p;
            rs += p;
          }
        l_i[nt] += rs;
        int prow = wave * 32 + nt * 16 + lr;
#pragma unroll
        for (int mt = 0; mt < 4; mt++) {
          u64 pw = (u64)pkbf(sc[mt][nt][0], sc[mt][nt][1]) |
                   ((u64)pkbf(sc[mt][nt][2], sc[mt][nt][3]) << 32);
          int bb = (mt * 2 + (lq >> 1)) ^ (lr & 7);
          *(u64*)((char*)Pt + prow * 128 + bb * 16 + (lq & 1) * 8) = pw;
        }
      }

#pragma unroll
      for (int kk2 = 0; kk2 < 2; kk2++) {
        bf16x8 pbf[2];
#pragma unroll
        for (int nt = 0; nt < 2; nt++) {
          int prow = wave * 32 + nt * 16 + lr;
          pbf[nt] = *(const bf16x8*)((char*)Pt + prow * 128 + (((kk2 * 4 + lq) ^ (lr & 7)) * 16));
        }
#pragma unroll
        for (int mt = 0; mt < 8; mt++) {
          bf16x8 vf = *(const bf16x8*)(V + (mt * 16 + lr) * 64 + (((kk2 * 4 + lq) ^ (lr & 7)) * 8));
#pragma unroll
          for (int nt = 0; nt < 2; nt++)
            o_acc[mt][nt] = __builtin_amdgcn_mfma_f32_16x16x32_bf16(vf, pbf[nt], o_acc[mt][nt], 0, 0, 0);
        }
      }
    }
  }

#pragma unroll
  for (int nt = 0; nt < 2; nt++) {
    float l = l_i[nt];
    l += __shfl_xor(l, 16, 64);
    l += __shfl_xor(l, 32, 64);
    float inv = 1.0f / l;
    size_t q = (size_t)q0 + wave * 32 + nt * 16 + lr;
    u16* dst = ob + ((size_t)b * SS + q) * HIDW + h * DD + lq * 4;
#pragma unroll
    for (int mt = 0; mt < 8; mt++) {
      uint2 pk;
      pk.x = pkbf(o_acc[mt][nt][0] * inv, o_acc[mt][nt][1] * inv);
      pk.y = pkbf(o_acc[mt][nt][2] * inv, o_acc[mt][nt][3] * inv);
      *(uint2*)(dst + mt * 16) = pk;
    }
  }
}

extern "C" void kernel_launch(void* const* d_in, const int* in_sizes, int n_in,
                              void* d_out, int out_size, void* d_ws, size_t ws_size,
                              hipStream_t stream) {
  const float* x = (const float*)d_in[0];
  const float* cosT = (const float*)d_in[1];
  const float* sinT = (const float*)d_in[2];
  const float* wq = (const float*)d_in[3];
  const float* wk = (const float*)d_in[4];
  const float* wv = (const float*)d_in[5];
  const float* wo = (const float*)d_in[6];
  float* out = (float*)d_out;

  char* ws = (char*)d_ws;
  size_t off = 0;
  auto alloc = [&](size_t bytes) {
    char* p = ws + off;
    off += (bytes + 255) & ~(size_t)255;
    return p;
  };
  const int M = BB * SS;
  u16* xb = (u16*)alloc((size_t)M * HIDW * 2);
  u16* wqkvb = (u16*)alloc((size_t)3072 * HIDW * 2);  // wq|wk|wv contiguous
  u16* wob = (u16*)alloc((size_t)HIDW * NH * DD * 2);
  u16* qb = (u16*)alloc((size_t)BB * NH * SS * DD * 2);
  u16* kb = (u16*)alloc((size_t)BB * NKV * SS * DD * 2);
  u16* vt = (u16*)alloc((size_t)BB * NKV * DD * SS * 2);
  u16* ob = (u16*)alloc((size_t)M * HIDW * 2);

  cast_f32_bf16<<<(M * HIDW) / 1024, 256, 0, stream>>>(x, xb, (M * HIDW) / 4);
  cast_weights<<<10240, 256, 0, stream>>>(wq, wk, wv, wo, wqkvb, wob);

  gemm_qkv_rope<<<dim3(3072 / 128, M / 128), 256, 0, stream>>>(xb, wqkvb, cosT, sinT,
                                                               qb, kb, vt);

  flash_attn<<<dim3(SS / 128, BB * NH), 256, 0, stream>>>(qb, kb, vt, ob);

  gemm_bt<<<dim3(HIDW / 128, M / 128), 256, 0, stream>>>(ob, wob, out, M, HIDW, NH * DD);
}

// Round 8
// 531.315 us; speedup vs baseline: 1.1543x; 1.0074x over previous
//
#include <hip/hip_runtime.h>
#include <stdint.h>

#define BB 4
#define SS 2048
#define HIDW 2048
#define NH 16
#define NKV 4
#define DD 128

typedef unsigned short u16;
typedef unsigned long long u64;
typedef unsigned int uint;
typedef __attribute__((ext_vector_type(8))) short bf16x8;
typedef __attribute__((ext_vector_type(4))) float f32x4;
typedef __attribute__((ext_vector_type(2))) float f32x2;
typedef __attribute__((ext_vector_type(2))) __bf16 bf16x2;

__device__ __forceinline__ u16 f2bf1(float f) {
  __bf16 h = (__bf16)f;
  return __builtin_bit_cast(u16, h);
}

__device__ __forceinline__ float bf2f(u16 v) {
  return __uint_as_float((uint)v << 16);
}

// packed f32 pair -> bf16 pair (v_cvt_pk_bf16_f32 on gfx950)
__device__ __forceinline__ uint pkbf(float a, float b) {
  f32x2 v = {a, b};
  bf16x2 h = __builtin_convertvector(v, bf16x2);
  return __builtin_bit_cast(uint, h);
}

__device__ __forceinline__ void gld_lds16(const void* g, void* s) {
  __builtin_amdgcn_global_load_lds(
      (const __attribute__((address_space(1))) void*)g,
      (__attribute__((address_space(3))) void*)(unsigned)(uintptr_t)s,
      16, 0, 0);
}

// ---------------- fp32 -> bf16 cast (x) ----------------
__global__ __launch_bounds__(256) void cast_f32_bf16(const float* __restrict__ in,
                                                     u16* __restrict__ out, int n4) {
  int i = blockIdx.x * 256 + threadIdx.x;
  if (i < n4) {
    float4 f = ((const float4*)in)[i];
    uint2 o;
    o.x = pkbf(f.x, f.y);
    o.y = pkbf(f.z, f.w);
    ((uint2*)out)[i] = o;
  }
}

// ---------------- all 4 weight casts in one launch ----------------
__global__ __launch_bounds__(256) void cast_weights(const float* __restrict__ wq,
                                                    const float* __restrict__ wk,
                                                    const float* __restrict__ wv,
                                                    const float* __restrict__ wo,
                                                    u16* __restrict__ wqkvb,
                                                    u16* __restrict__ wob) {
  int i = blockIdx.x * 256 + threadIdx.x;
  const float* src;
  uint2* dst;
  int off;
  if (i < 1048576) {
    src = wq; dst = (uint2*)wqkvb; off = i;
  } else if (i < 1310720) {
    src = wk; dst = (uint2*)(wqkvb + (size_t)2048 * 2048); off = i - 1048576;
  } else if (i < 1572864) {
    src = wv; dst = (uint2*)(wqkvb + (size_t)2560 * 2048); off = i - 1310720;
  } else {
    src = wo; dst = (uint2*)wob; off = i - 1572864;
  }
  float4 f = ((const float4*)src)[off];
  uint2 o;
  o.x = pkbf(f.x, f.y);
  o.y = pkbf(f.z, f.w);
  dst[off] = o;
}

// ---------------- m97-style GEMM: C(f32, MxN) = A(bf16 MxK) * Bt(bf16 NxK)^T ----
__global__ __launch_bounds__(256) void gemm_bt(const u16* __restrict__ A,
                                               const u16* __restrict__ Bt,
                                               float* __restrict__ C,
                                               int M, int N, int K) {
  __shared__ u16 As[128 * 32];
  __shared__ u16 Bs[128 * 32];
  const int tid = threadIdx.x;
  const int wave = tid >> 6, lane = tid & 63;
  const int lr = lane & 15, lq = lane >> 4;
  const int row0 = blockIdx.y * 128, col0 = blockIdx.x * 128;
  const int wm = (wave >> 1) * 64, wn = (wave & 1) * 64;

  const int trow = tid >> 2;
  const int tblk = (tid & 3) ^ (trow & 3);
  const u16* aSrc = A + (size_t)(row0 + trow) * K + tblk * 8;
  const u16* bSrc = Bt + (size_t)(col0 + trow) * K + tblk * 8;
  char* ldsA = (char*)As + wave * 1024;
  char* ldsB = (char*)Bs + wave * 1024;

  f32x4 acc[4][4] = {};
  const int aoff = (wm + lr) * 32 + ((lq ^ (lr & 3)) * 8);
  const int boff = (wn + lr) * 32 + ((lq ^ (lr & 3)) * 8);

  for (int k0 = 0; k0 < K; k0 += 32) {
    __syncthreads();
    gld_lds16(aSrc + k0, ldsA);
    gld_lds16(aSrc + (size_t)64 * K + k0, ldsA + 4096);
    gld_lds16(bSrc + k0, ldsB);
    gld_lds16(bSrc + (size_t)64 * K + k0, ldsB + 4096);
    __syncthreads();
    bf16x8 a[4], b[4];
#pragma unroll
    for (int i = 0; i < 4; i++) a[i] = *(const bf16x8*)(As + aoff + i * 512);
#pragma unroll
    for (int j = 0; j < 4; j++) b[j] = *(const bf16x8*)(Bs + boff + j * 512);
#pragma unroll
    for (int i = 0; i < 4; i++)
#pragma unroll
      for (int j = 0; j < 4; j++)
        acc[i][j] = __builtin_amdgcn_mfma_f32_16x16x32_bf16(a[i], b[j], acc[i][j], 0, 0, 0);
  }
#pragma unroll
  for (int i = 0; i < 4; i++) {
    int row = row0 + wm + i * 16 + lq * 4;
#pragma unroll
    for (int j = 0; j < 4; j++) {
      int col = col0 + wn + j * 16 + lr;
      float* cp = C + (size_t)row * N + col;
#pragma unroll
      for (int r = 0; r < 4; r++) cp[(size_t)r * N] = acc[i][j][r];
    }
  }
}

// ---------------- fused QKV GEMM + RoPE + head scatter + V transpose -----------
__global__ __launch_bounds__(256) void gemm_qkv_rope(const u16* __restrict__ A,
                                                     const u16* __restrict__ Bt,
                                                     const float* __restrict__ cosT,
                                                     const float* __restrict__ sinT,
                                                     u16* __restrict__ qb,
                                                     u16* __restrict__ kb,
                                                     u16* __restrict__ vt) {
  __shared__ u16 As[128 * 32];
  __shared__ u16 Bs[128 * 32];
  const int tid = threadIdx.x;
  const int wave = tid >> 6, lane = tid & 63;
  const int lr = lane & 15, lq = lane >> 4;
  const int row0 = blockIdx.y * 128, col0 = blockIdx.x * 128;
  const int K = HIDW;

  const int trow = tid >> 2;
  const int tblk = (tid & 3) ^ (trow & 3);
  const u16* aSrc = A + (size_t)(row0 + trow) * K + tblk * 8;
  const u16* bSrc = Bt + (size_t)(col0 + trow) * K + tblk * 8;
  char* ldsA = (char*)As + wave * 1024;
  char* ldsB = (char*)Bs + wave * 1024;

  f32x4 acc[2][8] = {};
  const int aoff = (wave * 32 + lr) * 32 + ((lq ^ (lr & 3)) * 8);
  const int boff = lr * 32 + ((lq ^ (lr & 3)) * 8);

  for (int k0 = 0; k0 < K; k0 += 32) {
    __syncthreads();
    gld_lds16(aSrc + k0, ldsA);
    gld_lds16(aSrc + (size_t)64 * K + k0, ldsA + 4096);
    gld_lds16(bSrc + k0, ldsB);
    gld_lds16(bSrc + (size_t)64 * K + k0, ldsB + 4096);
    __syncthreads();
    bf16x8 a[2], b[8];
#pragma unroll
    for (int i = 0; i < 2; i++) a[i] = *(const bf16x8*)(As + aoff + i * 512);
#pragma unroll
    for (int j = 0; j < 8; j++) b[j] = *(const bf16x8*)(Bs + boff + j * 512);
#pragma unroll
    for (int i = 0; i < 2; i++)
#pragma unroll
      for (int j = 0; j < 8; j++)
        acc[i][j] = __builtin_amdgcn_mfma_f32_16x16x32_bf16(a[i], b[j], acc[i][j], 0, 0, 0);
  }

  const int b_ = row0 >> 11;          // batch (tile never crosses: 2048%128==0)
  const int s_base = (row0 & (SS - 1)) + wave * 32;
  const int hsel = col0 >> 7;         // 0..15 q-head, 16..19 k-head, 20..23 v-head

  if (hsel < 20) {
    const float scale = (hsel < 16) ? 0.08838834764831845f : 1.0f;
    u16* base = (hsel < 16)
                    ? qb + (size_t)(b_ * NH + hsel) * SS * DD
                    : kb + (size_t)(b_ * NKV + (hsel - 16)) * SS * DD;
#pragma unroll
    for (int i = 0; i < 2; i++) {
#pragma unroll
      for (int r = 0; r < 4; r++) {
        int s = s_base + i * 16 + lq * 4 + r;
        const float* cp = cosT + (size_t)s * DD;
        const float* sp = sinT + (size_t)s * DD;
        u16* drow = base + (size_t)s * DD;
#pragma unroll
        for (int j = 0; j < 4; j++) {
          int d = j * 16 + lr;
          float c = cp[d], si = sp[d];
          float x0 = acc[i][j][r] * scale, x1 = acc[i][j + 4][r] * scale;
          drow[d] = f2bf1(x0 * c - x1 * si);
          drow[d + 64] = f2bf1(x1 * c + x0 * si);
        }
      }
    }
  } else {
    const int kv = hsel - 20;
#pragma unroll
    for (int i = 0; i < 2; i++) {
      int s = s_base + i * 16 + lq * 4;
#pragma unroll
      for (int j = 0; j < 8; j++) {
        int d = j * 16 + lr;
        u64 pw = (u64)pkbf(acc[i][j][0], acc[i][j][1]) |
                 ((u64)pkbf(acc[i][j][2], acc[i][j][3]) << 32);
        *(u64*)(vt + (size_t)((b_ * NKV + kv) * DD + d) * SS + s) = pw;
      }
    }
  }
}

// ---------------- transposed flash attention v4: cross-iteration prefetch ------
// K-loop restructured: barrier -> issue next tile's global_load_lds into the
// other buffer -> compute current tile. The ds_reads of compute are in the
// lgkmcnt domain and do NOT wait on the in-flight vmcnt prefetch; the next
// barrier's vmcnt(0) drain lands after ~2000 cyc of compute -> latency hidden.
// Exact softmax (scores bounded), 128 q-rows/block, 4 waves x 32 q.
__global__ __launch_bounds__(256, 2) void flash_attn(const u16* __restrict__ qb,
                                                     const u16* __restrict__ kb,
                                                     const u16* __restrict__ vt,
                                                     u16* __restrict__ ob) {
  __shared__ u16 Ks[2][64 * 128];  // [kv][d], 16B-blk swizzle ^ (row&15)
  __shared__ u16 Vs[2][128 * 64];  // [d][s],  16B-blk swizzle ^ (row&7)
  __shared__ u16 Pt[128 * 64];     // [q][kv], 16B-blk swizzle ^ (row&7)
  const int tid = threadIdx.x;
  const int wave = tid >> 6, lane = tid & 63;
  const int lr = lane & 15, lq = lane >> 4;

  const int lin = blockIdx.y * 16 + blockIdx.x;
  const int xcd = lin & 7;
  const int slot = lin >> 3;               // 0..127
  const int pr = xcd + ((slot & 1) << 3);  // (b,kvh) id 0..15
  const int b = pr >> 2, kvh = pr & 3;
  const int rest = slot >> 1;              // 0..63
  const int h = kvh * 4 + (rest & 3);
  const int q0 = (rest >> 2) * 128;
  const int bh = b * 16 + h;

  const size_t kbase = (size_t)(b * NKV + kvh) * SS * DD;
  const size_t vbase = (size_t)(b * NKV + kvh) * DD * SS;

  bf16x8 qf[2][4];
#pragma unroll
  for (int nt = 0; nt < 2; nt++) {
    const u16* qrow = qb + ((size_t)bh * SS + q0 + wave * 32 + nt * 16 + lr) * DD + lq * 8;
#pragma unroll
    for (int kk = 0; kk < 4; kk++) qf[nt][kk] = *(const bf16x8*)(qrow + kk * 32);
  }

  f32x4 o_acc[8][2] = {};
  float l_i[2] = {0.0f, 0.0f};

  const int ktrow = tid >> 4;
  const int ktblk = (tid & 15) ^ ktrow;
  const u16* ksrc = kb + kbase + (size_t)ktrow * DD + ktblk * 8;
  const int vtrow = tid >> 3;
  const int vtblk = (tid & 7) ^ (vtrow & 7);
  const u16* vsrc = vt + vbase + (size_t)vtrow * SS + vtblk * 8;

  // prologue: prefetch tile 0 into buffer 0
  {
    char* kd = (char*)(Ks[0]) + wave * 1024;
    char* vd = (char*)(Vs[0]) + wave * 1024;
#pragma unroll
    for (int c = 0; c < 4; c++) {
      gld_lds16(ksrc + (size_t)c * 16 * DD, kd + c * 4096);
      gld_lds16(vsrc + (size_t)c * 32 * SS, vd + c * 4096);
    }
  }

  for (int it = 0; it < SS / 64; it++) {
    __syncthreads();  // drains own prefetch (in flight for a whole compute phase)
    if (it + 1 < SS / 64) {
      int s0 = (it + 1) * 64;
      char* kd = (char*)(Ks[(it + 1) & 1]) + wave * 1024;
      char* vd = (char*)(Vs[(it + 1) & 1]) + wave * 1024;
#pragma unroll
      for (int c = 0; c < 4; c++) {
        gld_lds16(ksrc + (size_t)(s0 + c * 16) * DD, kd + c * 4096);
        gld_lds16(vsrc + s0 + (size_t)c * 32 * SS, vd + c * 4096);
      }
    }
    const u16* K = Ks[it & 1];
    const u16* V = Vs[it & 1];

    f32x4 sc[4][2] = {};
#pragma unroll
    for (int kk = 0; kk < 4; kk++) {
#pragma unroll
      for (int mt = 0; mt < 4; mt++) {
        bf16x8 kf = *(const bf16x8*)(K + (mt * 16 + lr) * 128 + (((kk * 4 + lq) ^ lr) * 8));
#pragma unroll
        for (int nt = 0; nt < 2; nt++)
          sc[mt][nt] = __builtin_amdgcn_mfma_f32_16x16x32_bf16(kf, qf[nt][kk], sc[mt][nt], 0, 0, 0);
      }
    }

#pragma unroll
    for (int nt = 0; nt < 2; nt++) {
      float rs = 0.0f;
#pragma unroll
      for (int mt = 0; mt < 4; mt++)
#pragma unroll
        for (int r = 0; r < 4; r++) {
          float p = __expf(sc[mt][nt][r]);
          sc[mt][nt][r] = p;
          rs += p;
        }
      l_i[nt] += rs;
      int prow = wave * 32 + nt * 16 + lr;
#pragma unroll
      for (int mt = 0; mt < 4; mt++) {
        u64 pw = (u64)pkbf(sc[mt][nt][0], sc[mt][nt][1]) |
                 ((u64)pkbf(sc[mt][nt][2], sc[mt][nt][3]) << 32);
        int bb = (mt * 2 + (lq >> 1)) ^ (lr & 7);
        *(u64*)((char*)Pt + prow * 128 + bb * 16 + (lq & 1) * 8) = pw;
      }
    }

#pragma unroll
    for (int kk2 = 0; kk2 < 2; kk2++) {
      bf16x8 pbf[2];
#pragma unroll
      for (int nt = 0; nt < 2; nt++) {
        int prow = wave * 32 + nt * 16 + lr;
        pbf[nt] = *(const bf16x8*)((char*)Pt + prow * 128 + (((kk2 * 4 + lq) ^ (lr & 7)) * 16));
      }
#pragma unroll
      for (int mt = 0; mt < 8; mt++) {
        bf16x8 vf = *(const bf16x8*)(V + (mt * 16 + lr) * 64 + (((kk2 * 4 + lq) ^ (lr & 7)) * 8));
#pragma unroll
        for (int nt = 0; nt < 2; nt++)
          o_acc[mt][nt] = __builtin_amdgcn_mfma_f32_16x16x32_bf16(vf, pbf[nt], o_acc[mt][nt], 0, 0, 0);
      }
    }
  }

#pragma unroll
  for (int nt = 0; nt < 2; nt++) {
    float l = l_i[nt];
    l += __shfl_xor(l, 16, 64);
    l += __shfl_xor(l, 32, 64);
    float inv = 1.0f / l;
    size_t q = (size_t)q0 + wave * 32 + nt * 16 + lr;
    u16* dst = ob + ((size_t)b * SS + q) * HIDW + h * DD + lq * 4;
#pragma unroll
    for (int mt = 0; mt < 8; mt++) {
      uint2 pk;
      pk.x = pkbf(o_acc[mt][nt][0] * inv, o_acc[mt][nt][1] * inv);
      pk.y = pkbf(o_acc[mt][nt][2] * inv, o_acc[mt][nt][3] * inv);
      *(uint2*)(dst + mt * 16) = pk;
    }
  }
}

extern "C" void kernel_launch(void* const* d_in, const int* in_sizes, int n_in,
                              void* d_out, int out_size, void* d_ws, size_t ws_size,
                              hipStream_t stream) {
  const float* x = (const float*)d_in[0];
  const float* cosT = (const float*)d_in[1];
  const float* sinT = (const float*)d_in[2];
  const float* wq = (const float*)d_in[3];
  const float* wk = (const float*)d_in[4];
  const float* wv = (const float*)d_in[5];
  const float* wo = (const float*)d_in[6];
  float* out = (float*)d_out;

  char* ws = (char*)d_ws;
  size_t off = 0;
  auto alloc = [&](size_t bytes) {
    char* p = ws + off;
    off += (bytes + 255) & ~(size_t)255;
    return p;
  };
  const int M = BB * SS;
  u16* xb = (u16*)alloc((size_t)M * HIDW * 2);
  u16* wqkvb = (u16*)alloc((size_t)3072 * HIDW * 2);  // wq|wk|wv contiguous
  u16* wob = (u16*)alloc((size_t)HIDW * NH * DD * 2);
  u16* qb = (u16*)alloc((size_t)BB * NH * SS * DD * 2);
  u16* kb = (u16*)alloc((size_t)BB * NKV * SS * DD * 2);
  u16* vt = (u16*)alloc((size_t)BB * NKV * DD * SS * 2);
  u16* ob = (u16*)alloc((size_t)M * HIDW * 2);

  cast_f32_bf16<<<(M * HIDW) / 1024, 256, 0, stream>>>(x, xb, (M * HIDW) / 4);
  cast_weights<<<10240, 256, 0, stream>>>(wq, wk, wv, wo, wqkvb, wob);

  gemm_qkv_rope<<<dim3(3072 / 128, M / 128), 256, 0, stream>>>(xb, wqkvb, cosT, sinT,
                                                               qb, kb, vt);

  flash_attn<<<dim3(SS / 128, BB * NH), 256, 0, stream>>>(qb, kb, vt, ob);

  gemm_bt<<<dim3(HIDW / 128, M / 128), 256, 0, stream>>>(ob, wob, out, M, HIDW, NH * DD);
}